// Round 1
// baseline (278.638 us; speedup 1.0000x reference)
//
#include <hip/hip_runtime.h>

// quadLayer: B=8, H=W=64, C=16, K=S=2, FM=32 -> oh=ow=32, 8192 locations,
// 8192 fp32 outputs per location (256 MB total). Memory-bound on output write.
//
// out[loc*8192 + c*512 + a*32 + f] =
//   sum_m p[a,m]*W1[c*128 + m*32 + f] + sum_q so[a,q]*W2[c*512 + q*32 + f]
// where p flat depth d = a*4+m maps to x[b, 2h+ki, 2w+kj, c16] with
// d = (ki*2+kj)*16 + c16, and so[a, m1*4+m2] = p[a,m1]*p[a,m2].

typedef float f4 __attribute__((ext_vector_type(4)));

#define LPB 4  // locations per block; 8192/4 = 2048 blocks

__global__ __launch_bounds__(256) void quad_kernel(
    const float* __restrict__ x,
    const float* __restrict__ W1,
    const float* __restrict__ W2,
    float* __restrict__ out)
{
    __shared__ __align__(16) float p_lds[64];    // patch, depth order (ki,kj,c)
    __shared__ __align__(16) float so_lds[256];  // outer products [a][16]

    const int t  = threadIdx.x;
    const int f4off = (t & 7) * 4;        // f in {0,4,...,28}
    const int s  = t >> 3;                // 0..31
    const int c  = s & 15;                // output channel c
    const int a0 = (s >> 4) * 8;          // a-range start: 0 or 8 (wave-uniform)

    // --- weights to registers: 20 float4 = 80 VGPRs, L1-resident loads ---
    f4 w1r[4];
    f4 w2r[16];
    {
        const float* W1p = W1 + c * 128 + f4off;
#pragma unroll
        for (int m = 0; m < 4; ++m)
            w1r[m] = *(const f4*)(W1p + m * 32);
        const float* W2p = W2 + c * 512 + f4off;
#pragma unroll
        for (int q = 0; q < 16; ++q)
            w2r[q] = *(const f4*)(W2p + q * 32);
    }

    const int loc0 = blockIdx.x * LPB;

    for (int i = 0; i < LPB; ++i) {
        const int loc = loc0 + i;
        const int b  = loc >> 10;         // /1024
        const int hw = loc & 1023;
        const int h  = hw >> 5;
        const int w  = hw & 31;

        __syncthreads();  // protect LDS reuse from previous iteration
        if (t < 16) {
            // 4 rows of 16 contiguous floats: x[b, 2h+ki, 2w+kj, 0:16]
            const int quad = t >> 2;            // (ki,kj)
            const int ki = quad >> 1, kj = quad & 1;
            const int l4 = (t & 3) * 4;
            const float* src =
                x + (((b * 64 + 2 * h + ki) * 64) + 2 * w + kj) * 16 + l4;
            *(f4*)&p_lds[quad * 16 + l4] = *(const f4*)src;
        }
        __syncthreads();
        {
            const int a = t >> 4, q = t & 15;
            so_lds[t] = p_lds[a * 4 + (q >> 2)] * p_lds[a * 4 + (q & 3)];
        }
        __syncthreads();

        float* outp = out + (size_t)loc * 8192 + c * 512 + f4off;

#pragma unroll
        for (int j = 0; j < 8; ++j) {
            const int a = a0 + j;  // wave-uniform -> LDS broadcast reads
            const f4 pv  = *(const f4*)&p_lds[a * 4];
            const f4 so0 = *(const f4*)&so_lds[a * 16];
            const f4 so1 = *(const f4*)&so_lds[a * 16 + 4];
            const f4 so2 = *(const f4*)&so_lds[a * 16 + 8];
            const f4 so3 = *(const f4*)&so_lds[a * 16 + 12];

            f4 acc = (f4)0.0f;
            acc += pv.x  * w1r[0];
            acc += pv.y  * w1r[1];
            acc += pv.z  * w1r[2];
            acc += pv.w  * w1r[3];
            acc += so0.x * w2r[0];
            acc += so0.y * w2r[1];
            acc += so0.z * w2r[2];
            acc += so0.w * w2r[3];
            acc += so1.x * w2r[4];
            acc += so1.y * w2r[5];
            acc += so1.z * w2r[6];
            acc += so1.w * w2r[7];
            acc += so2.x * w2r[8];
            acc += so2.y * w2r[9];
            acc += so2.z * w2r[10];
            acc += so2.w * w2r[11];
            acc += so3.x * w2r[12];
            acc += so3.y * w2r[13];
            acc += so3.z * w2r[14];
            acc += so3.w * w2r[15];

            __builtin_nontemporal_store(acc, (f4*)(outp + a * 32));
        }
    }
}

extern "C" void kernel_launch(void* const* d_in, const int* in_sizes, int n_in,
                              void* d_out, int out_size, void* d_ws, size_t ws_size,
                              hipStream_t stream) {
    const float* x  = (const float*)d_in[0];   // [8,64,64,16]
    const float* W1 = (const float*)d_in[1];   // [16,4,32]
    const float* W2 = (const float*)d_in[2];   // [16,16,32]
    float* out = (float*)d_out;                // [8,32,32,8192]

    const int n_loc = 8 * 32 * 32;             // 8192
    dim3 grid(n_loc / LPB), block(256);
    quad_kernel<<<grid, block, 0, stream>>>(x, W1, W2, out);
}